// Round 3
// baseline (91.998 us; speedup 1.0000x reference)
//
#include <hip/hip_runtime.h>
#include <math.h>

// Problem constants: N=2048, L=8, D=64, M=N=2048.
#define N_B 2048
#define L_L 8
#define D_D 64

typedef short bf16x8 __attribute__((ext_vector_type(8)));
typedef float f32x4 __attribute__((ext_vector_type(4)));
typedef short short8v __attribute__((ext_vector_type(8)));

// Split fp32 x into bf16 hi + bf16 lo (RTNE each), x ≈ hi + lo to ~2^-17 rel.
__device__ __forceinline__ void split_bf16(float x, unsigned short& hi,
                                           unsigned short& lo) {
  unsigned u = __float_as_uint(x);
  unsigned rb = u + 0x7FFFu + ((u >> 16) & 1u);
  unsigned hbits = rb & 0xFFFF0000u;
  hi = (unsigned short)(hbits >> 16);
  float res = x - __uint_as_float(hbits);
  unsigned u2 = __float_as_uint(res);
  unsigned rb2 = u2 + 0x7FFFu + ((u2 >> 16) & 1u);
  lo = (unsigned short)(rb2 >> 16);
}

// ---------------------------------------------------------------------------
// encode: z_multi[l][n][d] = (z @ enc_W^T + enc_b)[n][l*64+d]  (fp32, output)
// Also emits bf16 hi/lo split (zh/zl) and ||z_n||^2 (zn2) to workspace, so the
// hot lse kernel never does split arithmetic.
// grid 512: 8 n-rows per block, half the i-range (256 of 512).
// ---------------------------------------------------------------------------
__global__ __launch_bounds__(256) void encode_kernel(
    const float* __restrict__ z, const float* __restrict__ encW,
    const float* __restrict__ encb, float* __restrict__ zm,
    unsigned short* __restrict__ zhG, unsigned short* __restrict__ zlG,
    float* __restrict__ zn2G) {
  __shared__ float zrows[8][64];
  int n0 = (blockIdx.x >> 1) << 3;
  int i = ((blockIdx.x & 1) << 8) + threadIdx.x;
  if (threadIdx.x < 128) {
    int r = threadIdx.x >> 4, c = (threadIdx.x & 15) << 2;
    *(float4*)&zrows[r][c] = *(const float4*)(z + (n0 + r) * 64 + c);
  }
  __syncthreads();
  const float4* wr = (const float4*)(encW + (size_t)i * 64);
  float bi = encb[i];
  float acc[8];
  #pragma unroll
  for (int r = 0; r < 8; ++r) acc[r] = bi;
  #pragma unroll
  for (int k4 = 0; k4 < 16; ++k4) {
    float4 w = wr[k4];
    #pragma unroll
    for (int r = 0; r < 8; ++r) {
      float4 zv = *(float4*)&zrows[r][k4 << 2];
      acc[r] += w.x * zv.x + w.y * zv.y + w.z * zv.z + w.w * zv.w;
    }
  }
  int l = i >> 6, d = i & 63;
  #pragma unroll
  for (int r = 0; r < 8; ++r) {
    size_t idx = ((size_t)(l * N_B + n0 + r)) * 64 + d;
    zm[idx] = acc[r];
    unsigned short hi, lo;
    split_bf16(acc[r], hi, lo);
    zhG[idx] = hi;
    zlG[idx] = lo;
    float s = acc[r] * acc[r];   // wave-reduce over d (64 lanes = one l)
    s += __shfl_xor(s, 1);  s += __shfl_xor(s, 2);  s += __shfl_xor(s, 4);
    s += __shfl_xor(s, 8);  s += __shfl_xor(s, 16); s += __shfl_xor(s, 32);
    if (d == 0) zn2G[l * N_B + n0 + r] = s;
  }
}

// ---------------------------------------------------------------------------
// prep_e: split se*e into bf16 hi/lo (eh/el) + raw ||e_m||^2 (en2).
// One thread per (l,m) row. grid 64 x 256.
// ---------------------------------------------------------------------------
__global__ __launch_bounds__(256) void prep_e_kernel(
    const float* __restrict__ e, const float* __restrict__ log_sigma,
    unsigned short* __restrict__ ehG, unsigned short* __restrict__ elG,
    float* __restrict__ en2G) {
  int row = blockIdx.x * 256 + threadIdx.x;  // 0..16383
  const float ls = log_sigma[0];
  const float sig = __expf(ls);
  const float ap = (-1.0f / (2.0f * sig * sig)) * 1.4426950408889634f;
  const float se = -2.0f * ap;
  const float4* src = (const float4*)(e + (size_t)row * 64);
  float ssq = 0.f;
  #pragma unroll
  for (int j = 0; j < 8; ++j) {
    float4 a = src[2 * j], b = src[2 * j + 1];
    float v[8] = {a.x, a.y, a.z, a.w, b.x, b.y, b.z, b.w};
    short8v H, L;
    #pragma unroll
    for (int t = 0; t < 8; ++t) {
      ssq += v[t] * v[t];
      unsigned short hi, lo;
      split_bf16(se * v[t], hi, lo);
      H[t] = (short)hi;
      L[t] = (short)lo;
    }
    *(short8v*)&ehG[(size_t)row * 64 + j * 8] = H;
    *(short8v*)&elG[(size_t)row * 64 + j * 8] = L;
  }
  en2G[row] = ssq;
}

// ---------------------------------------------------------------------------
// lse: per (l, m-tile64, n-range512) block, 4 waves, 8 chunks of 64 n.
// partial[l][m][nb] = sum_n exp2( ap*||z_n||^2 - 2*ap*(z_n . e_m) )
// Pure staging (short8 copies) + 6 split-bf16 MFMAs + exp2. No online max
// (args bounded, verified round 2). LDS ~38KB -> 4 blocks/CU.
// ---------------------------------------------------------------------------
__global__ __launch_bounds__(256, 4) void lse_kernel(
    const unsigned short* __restrict__ zhG, const unsigned short* __restrict__ zlG,
    const unsigned short* __restrict__ ehG, const unsigned short* __restrict__ elG,
    const float* __restrict__ zn2G, const float* __restrict__ log_sigma,
    float* __restrict__ partials) {
  __shared__ __align__(16) unsigned short eh[64][72];
  __shared__ __align__(16) unsigned short el[64][72];
  __shared__ __align__(16) unsigned short zh[64][72];
  __shared__ __align__(16) unsigned short zl[64][72];
  __shared__ float azn2v[64];
  __shared__ float red[4][64];

  const int b = blockIdx.x;
  const int l = b >> 7;
  const int mt = (b >> 2) & 31;
  const int nb = b & 3;
  const int m0 = mt << 6;
  const int tid = threadIdx.x;
  const int lane = tid & 63;
  const int wave = tid >> 6;

  const float ls = log_sigma[0];
  const float sig = __expf(ls);
  const float ap = (-1.0f / (2.0f * sig * sig)) * 1.4426950408889634f;

  // ---- stage e tile (pre-split) ----
  {
    int r = tid >> 2, q = (tid & 3) << 4;
    size_t base = ((size_t)(l * N_B) + m0 + r) * 64 + q;
    *(short8v*)&eh[r][q]     = *(const short8v*)&ehG[base];
    *(short8v*)&eh[r][q + 8] = *(const short8v*)&ehG[base + 8];
    *(short8v*)&el[r][q]     = *(const short8v*)&elG[base];
    *(short8v*)&el[r][q + 8] = *(const short8v*)&elG[base + 8];
  }
  __syncthreads();

  // ---- hoist B fragments (e tile) into registers ----
  const int bm = lane & 15;
  const int k0 = (lane >> 4) << 3;
  bf16x8 Bh0[4], Bh1[4], Bl0[4], Bl1[4];
  #pragma unroll
  for (int ms = 0; ms < 4; ++ms) {
    Bh0[ms] = *(const bf16x8*)&eh[ms * 16 + bm][k0];
    Bh1[ms] = *(const bf16x8*)&eh[ms * 16 + bm][k0 + 32];
    Bl0[ms] = *(const bf16x8*)&el[ms * 16 + bm][k0];
    Bl1[ms] = *(const bf16x8*)&el[ms * 16 + bm][k0 + 32];
  }

  float sums[4] = {0.f, 0.f, 0.f, 0.f};

  for (int c = 0; c < 8; ++c) {
    int n0c = (nb << 9) + (c << 6);
    if (c) __syncthreads();
    {
      int r = tid >> 2, q = (tid & 3) << 4;
      size_t base = ((size_t)(l * N_B) + n0c + r) * 64 + q;
      *(short8v*)&zh[r][q]     = *(const short8v*)&zhG[base];
      *(short8v*)&zh[r][q + 8] = *(const short8v*)&zhG[base + 8];
      *(short8v*)&zl[r][q]     = *(const short8v*)&zlG[base];
      *(short8v*)&zl[r][q + 8] = *(const short8v*)&zlG[base + 8];
      if ((tid & 3) == 0) azn2v[r] = ap * zn2G[l * N_B + n0c + r];
    }
    __syncthreads();

    int row = (wave << 4) + bm;
    bf16x8 ah0 = *(const bf16x8*)&zh[row][k0];
    bf16x8 ah1 = *(const bf16x8*)&zh[row][k0 + 32];
    bf16x8 al0 = *(const bf16x8*)&zl[row][k0];
    bf16x8 al1 = *(const bf16x8*)&zl[row][k0 + 32];
    int rb = (wave << 4) + ((lane >> 4) << 2);
    float az0 = azn2v[rb + 0], az1 = azn2v[rb + 1];
    float az2 = azn2v[rb + 2], az3 = azn2v[rb + 3];
    #pragma unroll
    for (int ms = 0; ms < 4; ++ms) {
      f32x4 acc = {0.f, 0.f, 0.f, 0.f};
      acc = __builtin_amdgcn_mfma_f32_16x16x32_bf16(ah0, Bh0[ms], acc, 0, 0, 0);
      acc = __builtin_amdgcn_mfma_f32_16x16x32_bf16(ah1, Bh1[ms], acc, 0, 0, 0);
      acc = __builtin_amdgcn_mfma_f32_16x16x32_bf16(al0, Bh0[ms], acc, 0, 0, 0);
      acc = __builtin_amdgcn_mfma_f32_16x16x32_bf16(al1, Bh1[ms], acc, 0, 0, 0);
      acc = __builtin_amdgcn_mfma_f32_16x16x32_bf16(ah0, Bl0[ms], acc, 0, 0, 0);
      acc = __builtin_amdgcn_mfma_f32_16x16x32_bf16(ah1, Bl1[ms], acc, 0, 0, 0);
      sums[ms] += exp2f(acc[0] + az0) + exp2f(acc[1] + az1) +
                  exp2f(acc[2] + az2) + exp2f(acc[3] + az3);
    }
  }

  // ---- reduce lanes sharing a column, then waves ----
  #pragma unroll
  for (int ms = 0; ms < 4; ++ms) {
    float s = sums[ms];
    s += __shfl_xor(s, 16);
    s += __shfl_xor(s, 32);
    if (lane < 16) red[wave][ms * 16 + lane] = s;
  }
  __syncthreads();
  if (tid < 64) {
    float S = red[0][tid] + red[1][tid] + red[2][tid] + red[3][tid];
    partials[((size_t)(l * N_B) + m0 + tid) * 4 + nb] = S;
  }
}

// ---------------------------------------------------------------------------
// zdec: z_dec[n][d] = sum_{l,k} zm[l][n][k] * decW[d][l*64+k] + decb[d]
// ---------------------------------------------------------------------------
__global__ __launch_bounds__(256) void zdec_kernel(
    const float* __restrict__ zm, const float* __restrict__ decW,
    const float* __restrict__ decb, float* __restrict__ zdec) {
  int d = threadIdx.x & 63;
  int ns = threadIdx.x >> 6;
  int n0 = blockIdx.x * 16 + ns * 4;
  float bd = decb[d];
  float acc[4];
  #pragma unroll
  for (int r = 0; r < 4; ++r) acc[r] = bd;
  for (int l = 0; l < 8; ++l) {
    const float4* wr = (const float4*)(decW + (size_t)d * 512 + l * 64);
    const float* hbase = zm + ((size_t)l * N_B + n0) * 64;
    #pragma unroll
    for (int k4 = 0; k4 < 16; ++k4) {
      float4 w = wr[k4];
      #pragma unroll
      for (int r = 0; r < 4; ++r) {
        float4 h = *(const float4*)(hbase + r * 64 + (k4 << 2));
        acc[r] += w.x * h.x + w.y * h.y + w.z * h.z + w.w * h.w;
      }
    }
  }
  #pragma unroll
  for (int r = 0; r < 4; ++r)
    zdec[(n0 + r) * 64 + d] = acc[r];
}

// ---------------------------------------------------------------------------
// finalize1: per (l,m): S = sum of 4 nb-partials; lse = ln2*(ap*en2 + log2 S);
// block-sum -> bsums[64].
// ---------------------------------------------------------------------------
__global__ __launch_bounds__(256) void finalize1_kernel(
    const float* __restrict__ partials, const float* __restrict__ en2G,
    const float* __restrict__ log_sigma, float* __restrict__ bsums) {
  __shared__ float buf[256];
  int idx = blockIdx.x * 256 + threadIdx.x;
  const float ls = log_sigma[0];
  const float sig = __expf(ls);
  const float ap = (-1.0f / (2.0f * sig * sig)) * 1.4426950408889634f;

  float S = partials[idx * 4 + 0] + partials[idx * 4 + 1] +
            partials[idx * 4 + 2] + partials[idx * 4 + 3];
  float val = 0.69314718055994531f * (ap * en2G[idx] + log2f(S));

  buf[threadIdx.x] = val;
  __syncthreads();
  for (int s = 128; s; s >>= 1) {
    if (threadIdx.x < s) buf[threadIdx.x] += buf[threadIdx.x + s];
    __syncthreads();
  }
  if (threadIdx.x == 0) bsums[blockIdx.x] = buf[0];
}

__global__ __launch_bounds__(64) void finalize2_kernel(
    const float* __restrict__ bsums, const float* __restrict__ log_sigma,
    float* __restrict__ out_scalar) {
  float v = bsums[threadIdx.x];
  #pragma unroll
  for (int off = 32; off; off >>= 1) v += __shfl_down(v, off);
  if (threadIdx.x == 0) {
    float ls = log_sigma[0];
    float val = -v / (float)(L_L * N_B) + 0.5f * (float)D_D * (2.0f * ls - 1.0f)
              + logf((float)N_B);
    *out_scalar = val;
  }
}

extern "C" void kernel_launch(void* const* d_in, const int* in_sizes, int n_in,
                              void* d_out, int out_size, void* d_ws, size_t ws_size,
                              hipStream_t stream) {
  const float* z    = (const float*)d_in[0];
  const float* e    = (const float*)d_in[1];
  const float* encW = (const float*)d_in[2];
  const float* encb = (const float*)d_in[3];
  const float* decW = (const float*)d_in[4];
  const float* decb = (const float*)d_in[5];
  const float* lsg  = (const float*)d_in[6];

  float* out    = (float*)d_out;
  float* zdec   = out;                                // [2048*64]
  float* zmulti = out + N_B * D_D;                    // [8*2048*64]
  float* lse    = out + N_B * D_D + L_L * N_B * D_D;  // [1]

  float* partials = (float*)d_ws;                    // [8*2048*4]
  float* bsums    = partials + 65536;                // [64]
  float* zn2      = bsums + 64;                      // [8*2048]
  float* en2      = zn2 + 16384;                     // [8*2048]
  unsigned short* zh = (unsigned short*)(en2 + 16384);  // [1M]
  unsigned short* zl = zh + (1 << 20);
  unsigned short* ehg = zl + (1 << 20);
  unsigned short* elg = ehg + (1 << 20);

  encode_kernel<<<512, 256, 0, stream>>>(z, encW, encb, zmulti, zh, zl, zn2);
  prep_e_kernel<<<64, 256, 0, stream>>>(e, lsg, ehg, elg, en2);
  lse_kernel<<<1024, 256, 0, stream>>>(zh, zl, ehg, elg, zn2, lsg, partials);
  zdec_kernel<<<128, 256, 0, stream>>>(zmulti, decW, decb, zdec);
  finalize1_kernel<<<64, 256, 0, stream>>>(partials, en2, lsg, bsums);
  finalize2_kernel<<<1, 64, 0, stream>>>(bsums, lsg, lse);
}

// Round 5
// 85.720 us; speedup vs baseline: 1.0732x; 1.0732x over previous
//
#include <hip/hip_runtime.h>
#include <math.h>

// Problem constants: N=2048, L=8, D=64, M=N=2048.
#define N_B 2048
#define L_L 8
#define D_D 64

typedef short bf16x8 __attribute__((ext_vector_type(8)));
typedef float f32x4 __attribute__((ext_vector_type(4)));
typedef unsigned short ushort4v __attribute__((ext_vector_type(4)));

// Split fp32 x into bf16 hi + bf16 lo (RTNE each), x ≈ hi+lo to ~2^-17 rel.
__device__ __forceinline__ unsigned split_bf16_pack(float x) {
  unsigned u = __float_as_uint(x);
  unsigned rb = u + 0x7FFFu + ((u >> 16) & 1u);
  unsigned hbits = rb & 0xFFFF0000u;
  float res = x - __uint_as_float(hbits);
  unsigned u2 = __float_as_uint(res);
  unsigned rb2 = u2 + 0x7FFFu + ((u2 >> 16) & 1u);
  // hi in high 16, lo in low 16
  return hbits | (rb2 >> 16);
}

// ---------------------------------------------------------------------------
// encode (+zdec fused): per block 4 n-rows, full 512-i range.
//   h = z@encW^T + encb  (kept in LDS)
//   emits: zm (=z_multi output, fp32), zh/zl (bf16 split), az (=ap*||z_n||^2),
//          zdec (=h@decW^T + decb)
// ---------------------------------------------------------------------------
__global__ __launch_bounds__(256) void encode_kernel(
    const float* __restrict__ z, const float* __restrict__ encW,
    const float* __restrict__ encb, const float* __restrict__ decW,
    const float* __restrict__ decb, const float* __restrict__ log_sigma,
    float* __restrict__ zm, float* __restrict__ zdec,
    unsigned short* __restrict__ zhG, unsigned short* __restrict__ zlG,
    float* __restrict__ azG) {
  __shared__ float zrows[4][64];
  __shared__ float h[4][512];
  const int tid = threadIdx.x;
  const int n0 = blockIdx.x << 2;

  if (tid < 64) {
    int r = tid >> 4, c = (tid & 15) << 2;
    *(float4*)&zrows[r][c] = *(const float4*)(z + (n0 + r) * 64 + c);
  }
  __syncthreads();

  #pragma unroll
  for (int half = 0; half < 2; ++half) {
    int i = tid + half * 256;
    const float4* wr = (const float4*)(encW + (size_t)i * 64);
    float bi = encb[i];
    float a0 = bi, a1 = bi, a2 = bi, a3 = bi;
    #pragma unroll
    for (int k4 = 0; k4 < 16; ++k4) {
      float4 w = wr[k4];
      float4 z0 = *(float4*)&zrows[0][k4 << 2];
      float4 z1 = *(float4*)&zrows[1][k4 << 2];
      float4 z2 = *(float4*)&zrows[2][k4 << 2];
      float4 z3 = *(float4*)&zrows[3][k4 << 2];
      a0 += w.x * z0.x + w.y * z0.y + w.z * z0.z + w.w * z0.w;
      a1 += w.x * z1.x + w.y * z1.y + w.z * z1.z + w.w * z1.w;
      a2 += w.x * z2.x + w.y * z2.y + w.z * z2.z + w.w * z2.w;
      a3 += w.x * z3.x + w.y * z3.y + w.z * z3.z + w.w * z3.w;
    }
    h[0][i] = a0; h[1][i] = a1; h[2][i] = a2; h[3][i] = a3;
  }
  __syncthreads();

  // ---- write pass: zm / zh / zl / az from LDS h ----
  {
    const float ls = log_sigma[0];
    const float sig = __expf(ls);
    const float ap = (-1.0f / (2.0f * sig * sig)) * 1.4426950408889634f;
    int q0 = tid << 1;          // first of 2 quads
    int r = q0 >> 7;            // row 0..3
    int qq = q0 & 127;          // quad within row
    int l = qq >> 4;            // 0..7 (both quads same l)
    int dq = (qq & 15) << 2;    // d offset
    size_t base = ((size_t)(l * N_B + n0 + r)) * 64 + dq;
    float ssq = 0.f;
    #pragma unroll
    for (int j = 0; j < 2; ++j) {
      float4 v = *(float4*)&h[r][(qq + j) << 2];
      *(float4*)(zm + base + j * 4) = v;
      unsigned px = split_bf16_pack(v.x);
      unsigned py = split_bf16_pack(v.y);
      unsigned pz = split_bf16_pack(v.z);
      unsigned pw = split_bf16_pack(v.w);
      ushort4v H = {(unsigned short)(px >> 16), (unsigned short)(py >> 16),
                    (unsigned short)(pz >> 16), (unsigned short)(pw >> 16)};
      ushort4v L = {(unsigned short)(px & 0xFFFF), (unsigned short)(py & 0xFFFF),
                    (unsigned short)(pz & 0xFFFF), (unsigned short)(pw & 0xFFFF)};
      *(ushort4v*)(zhG + base + j * 4) = H;
      *(ushort4v*)(zlG + base + j * 4) = L;
      ssq += v.x * v.x + v.y * v.y + v.z * v.z + v.w * v.w;
    }
    ssq += __shfl_xor(ssq, 1);
    ssq += __shfl_xor(ssq, 2);
    ssq += __shfl_xor(ssq, 4);
    if ((tid & 7) == 0) azG[l * N_B + n0 + r] = ap * ssq;
  }

  // ---- zdec: one output per thread ----
  {
    int d = tid & 63, g = tid >> 6;
    const float4* wr = (const float4*)(decW + (size_t)d * 512);
    float acc = decb[d];
    #pragma unroll 8
    for (int i4 = 0; i4 < 128; ++i4) {
      float4 w = wr[i4];
      float4 hv = *(float4*)&h[g][i4 << 2];
      acc += w.x * hv.x + w.y * hv.y + w.z * hv.z + w.w * hv.w;
    }
    zdec[(n0 + g) * 64 + d] = acc;
  }
}

// ---------------------------------------------------------------------------
// lse: grid 1024 = l(8) x mt(32) x nb(4), XCD-swizzled so each XCD owns one l.
// No LDS staging, no in-loop barriers: A-frags (z hi/lo) loaded directly from
// global (L2-hot, contiguous 2KB per instr), B-frags (e) built in-register
// (scale by -2*ap, hi/lo split) in the prologue. nb==0 blocks also emit
// ||e_m||^2. Per wave: 8 independent chunks of 16 n-rows.
// partial[l][m][nb] = sum_n exp2( az_n + (-2ap) z_n.e_m )   [base-2 domain]
// ---------------------------------------------------------------------------
__global__ __launch_bounds__(256, 3) void lse_kernel(
    const unsigned short* __restrict__ zhG, const unsigned short* __restrict__ zlG,
    const float* __restrict__ e, const float* __restrict__ azG,
    const float* __restrict__ log_sigma,
    float* __restrict__ partials, float* __restrict__ en2G) {
  __shared__ float red[4][64];
  // XCD swizzle: xcd = blockIdx.x % 8 gets contiguous wgid chunk = one l.
  const int wgid = (blockIdx.x & 7) * 128 + (blockIdx.x >> 3);
  const int l = wgid >> 7;
  const int mt = (wgid >> 2) & 31;
  const int nb = wgid & 3;
  const int m0 = mt << 6;
  const int tid = threadIdx.x;
  const int lane = tid & 63;
  const int wave = tid >> 6;
  const int bm = lane & 15;
  const int kg = lane >> 4;   // 0..3
  const int k0 = kg << 3;     // 0,8,16,24

  const float ls = log_sigma[0];
  const float sig = __expf(ls);
  const float ap = (-1.0f / (2.0f * sig * sig)) * 1.4426950408889634f;
  const float se = -2.0f * ap;

  // ---- B fragments straight from e (scale + split in reg) ----
  bf16x8 Bh0[4], Bh1[4], Bl0[4], Bl1[4];
  #pragma unroll
  for (int ms = 0; ms < 4; ++ms) {
    const float* er = e + ((size_t)(l * N_B) + m0 + ms * 16 + bm) * 64;
    float4 a0 = *(const float4*)(er + k0);
    float4 a1 = *(const float4*)(er + k0 + 4);
    float4 b0 = *(const float4*)(er + k0 + 32);
    float4 b1 = *(const float4*)(er + k0 + 36);
    float vv[16] = {a0.x, a0.y, a0.z, a0.w, a1.x, a1.y, a1.z, a1.w,
                    b0.x, b0.y, b0.z, b0.w, b1.x, b1.y, b1.z, b1.w};
    float ssq = 0.f;
    bf16x8 H0, L0, H1, L1;
    #pragma unroll
    for (int t = 0; t < 8; ++t) {
      ssq += vv[t] * vv[t] + vv[8 + t] * vv[8 + t];
      unsigned p0 = split_bf16_pack(se * vv[t]);
      H0[t] = (short)(p0 >> 16); L0[t] = (short)(p0 & 0xFFFF);
      unsigned p1 = split_bf16_pack(se * vv[8 + t]);
      H1[t] = (short)(p1 >> 16); L1[t] = (short)(p1 & 0xFFFF);
    }
    Bh0[ms] = H0; Bl0[ms] = L0; Bh1[ms] = H1; Bl1[ms] = L1;
    if (nb == 0) {
      ssq += __shfl_xor(ssq, 16);
      ssq += __shfl_xor(ssq, 32);
      if (kg == 0) en2G[(size_t)(l * N_B) + m0 + ms * 16 + bm] = ssq;
    }
  }

  float sums[4] = {0.f, 0.f, 0.f, 0.f};
  const unsigned short* zhL = zhG + (size_t)(l * N_B) * 64;
  const unsigned short* zlL = zlG + (size_t)(l * N_B) * 64;
  const float* azL = azG + l * N_B;

  #pragma unroll 2
  for (int c = 0; c < 8; ++c) {
    const int n0c = (nb << 9) + (((c << 2) + wave) << 4);
    const size_t abase = ((size_t)(n0c + bm)) * 64 + k0;
    bf16x8 ah0 = *(const bf16x8*)(zhL + abase);
    bf16x8 ah1 = *(const bf16x8*)(zhL + abase + 32);
    bf16x8 al0 = *(const bf16x8*)(zlL + abase);
    bf16x8 al1 = *(const bf16x8*)(zlL + abase + 32);
    f32x4 azv = *(const f32x4*)(azL + n0c + (kg << 2));
    #pragma unroll
    for (int ms = 0; ms < 4; ++ms) {
      f32x4 acc = {0.f, 0.f, 0.f, 0.f};
      acc = __builtin_amdgcn_mfma_f32_16x16x32_bf16(ah0, Bh0[ms], acc, 0, 0, 0);
      acc = __builtin_amdgcn_mfma_f32_16x16x32_bf16(ah1, Bh1[ms], acc, 0, 0, 0);
      acc = __builtin_amdgcn_mfma_f32_16x16x32_bf16(al0, Bh0[ms], acc, 0, 0, 0);
      acc = __builtin_amdgcn_mfma_f32_16x16x32_bf16(al1, Bh1[ms], acc, 0, 0, 0);
      acc = __builtin_amdgcn_mfma_f32_16x16x32_bf16(ah0, Bl0[ms], acc, 0, 0, 0);
      acc = __builtin_amdgcn_mfma_f32_16x16x32_bf16(ah1, Bl1[ms], acc, 0, 0, 0);
      sums[ms] += exp2f(acc[0] + azv[0]) + exp2f(acc[1] + azv[1]) +
                  exp2f(acc[2] + azv[2]) + exp2f(acc[3] + azv[3]);
    }
  }

  // ---- reduce: k-groups within wave, then 4 waves via LDS ----
  #pragma unroll
  for (int ms = 0; ms < 4; ++ms) {
    float s = sums[ms];
    s += __shfl_xor(s, 16);
    s += __shfl_xor(s, 32);
    if (lane < 16) red[wave][ms * 16 + lane] = s;
  }
  __syncthreads();
  if (tid < 64) {
    float S = red[0][tid] + red[1][tid] + red[2][tid] + red[3][tid];
    partials[(((size_t)(l * N_B)) + m0 + tid) * 4 + nb] = S;
  }
}

// ---------------------------------------------------------------------------
// finalize1: per (l,m): S = sum of 4 nb-partials; val = ln2*(ap*en2+log2 S);
// block-sum -> bsums[64].
// ---------------------------------------------------------------------------
__global__ __launch_bounds__(256) void finalize1_kernel(
    const float* __restrict__ partials, const float* __restrict__ en2G,
    const float* __restrict__ log_sigma, float* __restrict__ bsums) {
  __shared__ float buf[256];
  int idx = blockIdx.x * 256 + threadIdx.x;
  const float ls = log_sigma[0];
  const float sig = __expf(ls);
  const float ap = (-1.0f / (2.0f * sig * sig)) * 1.4426950408889634f;

  f32x4 p = *(const f32x4*)(partials + (size_t)idx * 4);
  float S = p[0] + p[1] + p[2] + p[3];
  float val = 0.69314718055994531f * (ap * en2G[idx] + log2f(S));

  buf[threadIdx.x] = val;
  __syncthreads();
  for (int s = 128; s; s >>= 1) {
    if (threadIdx.x < s) buf[threadIdx.x] += buf[threadIdx.x + s];
    __syncthreads();
  }
  if (threadIdx.x == 0) bsums[blockIdx.x] = buf[0];
}

__global__ __launch_bounds__(64) void finalize2_kernel(
    const float* __restrict__ bsums, const float* __restrict__ log_sigma,
    float* __restrict__ out_scalar) {
  float v = bsums[threadIdx.x];
  #pragma unroll
  for (int off = 32; off; off >>= 1) v += __shfl_down(v, off);
  if (threadIdx.x == 0) {
    float ls = log_sigma[0];
    float val = -v / (float)(L_L * N_B) + 0.5f * (float)D_D * (2.0f * ls - 1.0f)
              + logf((float)N_B);
    *out_scalar = val;
  }
}

extern "C" void kernel_launch(void* const* d_in, const int* in_sizes, int n_in,
                              void* d_out, int out_size, void* d_ws, size_t ws_size,
                              hipStream_t stream) {
  const float* z    = (const float*)d_in[0];
  const float* e    = (const float*)d_in[1];
  const float* encW = (const float*)d_in[2];
  const float* encb = (const float*)d_in[3];
  const float* decW = (const float*)d_in[4];
  const float* decb = (const float*)d_in[5];
  const float* lsg  = (const float*)d_in[6];

  float* out    = (float*)d_out;
  float* zdec   = out;                                // [2048*64]
  float* zmulti = out + N_B * D_D;                    // [8*2048*64]
  float* lse    = out + N_B * D_D + L_L * N_B * D_D;  // [1]

  float* partials = (float*)d_ws;                     // [8*2048*4]
  float* bsums    = partials + 65536;                 // [64]
  float* az       = bsums + 64;                       // [8*2048]
  float* en2      = az + 16384;                       // [8*2048]
  unsigned short* zh = (unsigned short*)(en2 + 16384);  // [8*2048*64]
  unsigned short* zl = zh + (1 << 20);

  encode_kernel<<<512, 256, 0, stream>>>(z, encW, encb, decW, decb, lsg,
                                         zmulti, zdec, zh, zl, az);
  lse_kernel<<<1024, 256, 0, stream>>>(zh, zl, e, az, lsg, partials, en2);
  finalize1_kernel<<<64, 256, 0, stream>>>(partials, en2, lsg, bsums);
  finalize2_kernel<<<1, 64, 0, stream>>>(bsums, lsg, lse);
}

// Round 6
// 61.839 us; speedup vs baseline: 1.4877x; 1.3862x over previous
//
#include <hip/hip_runtime.h>
#include <math.h>

// Problem constants: N=2048, L=8, D=64, M=N=2048.
#define N_B 2048
#define L_L 8
#define D_D 64

typedef short bf16x8 __attribute__((ext_vector_type(8)));
typedef float f32x4 __attribute__((ext_vector_type(4)));

// Split fp32 x into bf16 hi + bf16 lo (RTNE each), x ≈ hi+lo to ~2^-17 rel.
// Returns hi in high 16 bits, lo in low 16 bits.
__device__ __forceinline__ unsigned split_bf16_pack(float x) {
  unsigned u = __float_as_uint(x);
  unsigned rb = u + 0x7FFFu + ((u >> 16) & 1u);
  unsigned hbits = rb & 0xFFFF0000u;
  float res = x - __uint_as_float(hbits);
  unsigned u2 = __float_as_uint(res);
  unsigned rb2 = u2 + 0x7FFFu + ((u2 >> 16) & 1u);
  return hbits | (rb2 >> 16);
}

// Load 16 floats (k0..k0+7, k0+32..k0+39) from row base, split into 4 frags.
__device__ __forceinline__ void load_split_row(const float* __restrict__ base,
                                               int k0, float scale,
                                               bf16x8& H0, bf16x8& L0,
                                               bf16x8& H1, bf16x8& L1,
                                               float* ssq) {
  float4 a0 = *(const float4*)(base + k0);
  float4 a1 = *(const float4*)(base + k0 + 4);
  float4 b0 = *(const float4*)(base + k0 + 32);
  float4 b1 = *(const float4*)(base + k0 + 36);
  float vv[16] = {a0.x, a0.y, a0.z, a0.w, a1.x, a1.y, a1.z, a1.w,
                  b0.x, b0.y, b0.z, b0.w, b1.x, b1.y, b1.z, b1.w};
  #pragma unroll
  for (int t = 0; t < 8; ++t) {
    if (ssq) *ssq += vv[t] * vv[t] + vv[8 + t] * vv[8 + t];
    unsigned p0 = split_bf16_pack(scale * vv[t]);
    H0[t] = (short)(p0 >> 16); L0[t] = (short)(p0 & 0xFFFF);
    unsigned p1 = split_bf16_pack(scale * vv[8 + t]);
    H1[t] = (short)(p1 >> 16); L1[t] = (short)(p1 & 0xFFFF);
  }
}

// ---------------------------------------------------------------------------
// encode: h = z @ encW^T + encb as z_multi[l][n][d], via split-bf16 MFMA.
// grid 256 = ntile(32) x l(8), l = bid&7 (one l per XCD). Block 256 = 4 waves,
// each wave 16 n-rows. Emits zm (fp32), zh/zl (bf16 split of h), az.
// nt==0 blocks also pre-split decW chunk for their l into dwh/dwl.
// ---------------------------------------------------------------------------
__global__ __launch_bounds__(256) void encode_kernel(
    const float* __restrict__ z, const float* __restrict__ encW,
    const float* __restrict__ encb, const float* __restrict__ decW,
    const float* __restrict__ log_sigma,
    float* __restrict__ zm,
    unsigned short* __restrict__ zhG, unsigned short* __restrict__ zlG,
    float* __restrict__ azG,
    unsigned short* __restrict__ dwh, unsigned short* __restrict__ dwl) {
  const int l = blockIdx.x & 7;
  const int nt = blockIdx.x >> 3;
  const int n0 = nt << 6;
  const int tid = threadIdx.x;
  const int lane = tid & 63;
  const int wave = tid >> 6;
  const int bm = lane & 15;
  const int kg = lane >> 4;
  const int k0 = kg << 3;

  // ---- side job: pre-split decW[:, l*64:(l+1)*64] into dwh/dwl ----
  if (nt == 0) {
    int d = tid >> 2, c0 = (tid & 3) << 4;
    const float* src = decW + (size_t)d * 512 + l * 64 + c0;
    unsigned short* dh = dwh + (size_t)d * 512 + l * 64 + c0;
    unsigned short* dl = dwl + (size_t)d * 512 + l * 64 + c0;
    #pragma unroll
    for (int j = 0; j < 4; ++j) {
      float4 v = *(const float4*)(src + j * 4);
      unsigned px = split_bf16_pack(v.x), py = split_bf16_pack(v.y);
      unsigned pz = split_bf16_pack(v.z), pw = split_bf16_pack(v.w);
      dh[j * 4 + 0] = (unsigned short)(px >> 16);
      dh[j * 4 + 1] = (unsigned short)(py >> 16);
      dh[j * 4 + 2] = (unsigned short)(pz >> 16);
      dh[j * 4 + 3] = (unsigned short)(pw >> 16);
      dl[j * 4 + 0] = (unsigned short)(px & 0xFFFF);
      dl[j * 4 + 1] = (unsigned short)(py & 0xFFFF);
      dl[j * 4 + 2] = (unsigned short)(pz & 0xFFFF);
      dl[j * 4 + 3] = (unsigned short)(pw & 0xFFFF);
    }
  }

  const float ls = log_sigma[0];
  const float sig = __expf(ls);
  const float ap = (-1.0f / (2.0f * sig * sig)) * 1.4426950408889634f;

  // ---- B fragments: encW rows i = l*64 + ms*16 + bm ----
  bf16x8 Bh0[4], Bh1[4], Bl0[4], Bl1[4];
  #pragma unroll
  for (int ms = 0; ms < 4; ++ms) {
    int i = l * 64 + ms * 16 + bm;
    load_split_row(encW + (size_t)i * 64, k0, 1.0f,
                   Bh0[ms], Bl0[ms], Bh1[ms], Bl1[ms], nullptr);
  }

  // ---- A fragments: z rows n = n0 + wave*16 + bm ----
  bf16x8 ah0, al0, ah1, al1;
  {
    int n = n0 + (wave << 4) + bm;
    load_split_row(z + (size_t)n * 64, k0, 1.0f, ah0, al0, ah1, al1, nullptr);
  }

  // ---- acc init with encb, then 6 MFMAs per ms ----
  float sq[4] = {0.f, 0.f, 0.f, 0.f};
  #pragma unroll
  for (int ms = 0; ms < 4; ++ms) {
    float bi = encb[l * 64 + ms * 16 + bm];
    f32x4 acc = {bi, bi, bi, bi};
    acc = __builtin_amdgcn_mfma_f32_16x16x32_bf16(ah0, Bh0[ms], acc, 0, 0, 0);
    acc = __builtin_amdgcn_mfma_f32_16x16x32_bf16(ah1, Bh1[ms], acc, 0, 0, 0);
    acc = __builtin_amdgcn_mfma_f32_16x16x32_bf16(al0, Bh0[ms], acc, 0, 0, 0);
    acc = __builtin_amdgcn_mfma_f32_16x16x32_bf16(al1, Bh1[ms], acc, 0, 0, 0);
    acc = __builtin_amdgcn_mfma_f32_16x16x32_bf16(ah0, Bl0[ms], acc, 0, 0, 0);
    acc = __builtin_amdgcn_mfma_f32_16x16x32_bf16(ah1, Bl1[ms], acc, 0, 0, 0);
    // epilogue: C layout row = kg*4 + r, col = ms*16 + bm
    #pragma unroll
    for (int r = 0; r < 4; ++r) {
      float v = acc[r];
      int nr = n0 + (wave << 4) + (kg << 2) + r;
      size_t idx = ((size_t)(l * N_B + nr)) * 64 + (ms << 4) + bm;
      zm[idx] = v;
      unsigned p = split_bf16_pack(v);
      zhG[idx] = (unsigned short)(p >> 16);
      zlG[idx] = (unsigned short)(p & 0xFFFF);
      sq[r] += v * v;
    }
  }
  // ---- az = ap * ||h_row||^2 : reduce over bm (cols) ----
  #pragma unroll
  for (int r = 0; r < 4; ++r) {
    float s = sq[r];
    s += __shfl_xor(s, 1);
    s += __shfl_xor(s, 2);
    s += __shfl_xor(s, 4);
    s += __shfl_xor(s, 8);
    if (bm == 0)
      azG[l * N_B + n0 + (wave << 4) + (kg << 2) + r] = ap * s;
  }
}

// ---------------------------------------------------------------------------
// zdec: z_dec = h @ decW^T + decb via split-bf16 MFMA over K=512.
// All operands pre-split (zh/zl, dwh/dwl). 128 blocks x 1 wave, 16 n each.
// ---------------------------------------------------------------------------
__global__ __launch_bounds__(64) void zdec_kernel(
    const unsigned short* __restrict__ zhG, const unsigned short* __restrict__ zlG,
    const unsigned short* __restrict__ dwh, const unsigned short* __restrict__ dwl,
    const float* __restrict__ decb, float* __restrict__ zdec) {
  const int nt = blockIdx.x;
  const int n0 = nt << 4;
  const int lane = threadIdx.x;
  const int bm = lane & 15;
  const int kg = lane >> 4;
  const int k0 = kg << 3;

  f32x4 acc[4];
  #pragma unroll
  for (int ms = 0; ms < 4; ++ms) {
    float bd = decb[(ms << 4) + bm];
    acc[ms] = {bd, bd, bd, bd};
  }

  #pragma unroll 4
  for (int j = 0; j < 16; ++j) {
    int l = j >> 1;
    int off = ((j & 1) << 5) + k0;
    size_t ab = ((size_t)(l * N_B + n0 + bm)) * 64 + off;
    bf16x8 ah = *(const bf16x8*)(zhG + ab);
    bf16x8 al = *(const bf16x8*)(zlG + ab);
    #pragma unroll
    for (int ms = 0; ms < 4; ++ms) {
      int d = (ms << 4) + bm;
      size_t bb = (size_t)d * 512 + (j << 5) + k0;
      bf16x8 bh = *(const bf16x8*)(dwh + bb);
      bf16x8 bl = *(const bf16x8*)(dwl + bb);
      acc[ms] = __builtin_amdgcn_mfma_f32_16x16x32_bf16(ah, bh, acc[ms], 0, 0, 0);
      acc[ms] = __builtin_amdgcn_mfma_f32_16x16x32_bf16(al, bh, acc[ms], 0, 0, 0);
      acc[ms] = __builtin_amdgcn_mfma_f32_16x16x32_bf16(ah, bl, acc[ms], 0, 0, 0);
    }
  }

  #pragma unroll
  for (int ms = 0; ms < 4; ++ms)
    #pragma unroll
    for (int r = 0; r < 4; ++r)
      zdec[(size_t)(n0 + (kg << 2) + r) * 64 + (ms << 4) + bm] = acc[ms][r];
}

// ---------------------------------------------------------------------------
// lse: unchanged from round 5 (grid 1024 = l x mt x nb, XCD-swizzled, no LDS
// staging, no in-loop barriers).
// ---------------------------------------------------------------------------
__global__ __launch_bounds__(256, 3) void lse_kernel(
    const unsigned short* __restrict__ zhG, const unsigned short* __restrict__ zlG,
    const float* __restrict__ e, const float* __restrict__ azG,
    const float* __restrict__ log_sigma,
    float* __restrict__ partials, float* __restrict__ en2G) {
  __shared__ float red[4][64];
  const int wgid = (blockIdx.x & 7) * 128 + (blockIdx.x >> 3);
  const int l = wgid >> 7;
  const int mt = (wgid >> 2) & 31;
  const int nb = wgid & 3;
  const int m0 = mt << 6;
  const int tid = threadIdx.x;
  const int lane = tid & 63;
  const int wave = tid >> 6;
  const int bm = lane & 15;
  const int kg = lane >> 4;
  const int k0 = kg << 3;

  const float ls = log_sigma[0];
  const float sig = __expf(ls);
  const float ap = (-1.0f / (2.0f * sig * sig)) * 1.4426950408889634f;
  const float se = -2.0f * ap;

  bf16x8 Bh0[4], Bh1[4], Bl0[4], Bl1[4];
  #pragma unroll
  for (int ms = 0; ms < 4; ++ms) {
    float ssq = 0.f;
    load_split_row(e + ((size_t)(l * N_B) + m0 + ms * 16 + bm) * 64, k0, se,
                   Bh0[ms], Bl0[ms], Bh1[ms], Bl1[ms], &ssq);
    if (nb == 0) {
      ssq += __shfl_xor(ssq, 16);
      ssq += __shfl_xor(ssq, 32);
      if (kg == 0) en2G[(size_t)(l * N_B) + m0 + ms * 16 + bm] = ssq;
    }
  }

  float sums[4] = {0.f, 0.f, 0.f, 0.f};
  const unsigned short* zhL = zhG + (size_t)(l * N_B) * 64;
  const unsigned short* zlL = zlG + (size_t)(l * N_B) * 64;
  const float* azL = azG + l * N_B;

  #pragma unroll 2
  for (int c = 0; c < 8; ++c) {
    const int n0c = (nb << 9) + (((c << 2) + wave) << 4);
    const size_t abase = ((size_t)(n0c + bm)) * 64 + k0;
    bf16x8 ah0 = *(const bf16x8*)(zhL + abase);
    bf16x8 ah1 = *(const bf16x8*)(zhL + abase + 32);
    bf16x8 al0 = *(const bf16x8*)(zlL + abase);
    bf16x8 al1 = *(const bf16x8*)(zlL + abase + 32);
    f32x4 azv = *(const f32x4*)(azL + n0c + (kg << 2));
    #pragma unroll
    for (int ms = 0; ms < 4; ++ms) {
      f32x4 acc = {0.f, 0.f, 0.f, 0.f};
      acc = __builtin_amdgcn_mfma_f32_16x16x32_bf16(ah0, Bh0[ms], acc, 0, 0, 0);
      acc = __builtin_amdgcn_mfma_f32_16x16x32_bf16(ah1, Bh1[ms], acc, 0, 0, 0);
      acc = __builtin_amdgcn_mfma_f32_16x16x32_bf16(al0, Bh0[ms], acc, 0, 0, 0);
      acc = __builtin_amdgcn_mfma_f32_16x16x32_bf16(al1, Bh1[ms], acc, 0, 0, 0);
      acc = __builtin_amdgcn_mfma_f32_16x16x32_bf16(ah0, Bl0[ms], acc, 0, 0, 0);
      acc = __builtin_amdgcn_mfma_f32_16x16x32_bf16(ah1, Bl1[ms], acc, 0, 0, 0);
      sums[ms] += exp2f(acc[0] + azv[0]) + exp2f(acc[1] + azv[1]) +
                  exp2f(acc[2] + azv[2]) + exp2f(acc[3] + azv[3]);
    }
  }

  #pragma unroll
  for (int ms = 0; ms < 4; ++ms) {
    float s = sums[ms];
    s += __shfl_xor(s, 16);
    s += __shfl_xor(s, 32);
    if (lane < 16) red[wave][ms * 16 + lane] = s;
  }
  __syncthreads();
  if (tid < 64) {
    float S = red[0][tid] + red[1][tid] + red[2][tid] + red[3][tid];
    partials[(((size_t)(l * N_B)) + m0 + tid) * 4 + nb] = S;
  }
}

// ---------------------------------------------------------------------------
// finalize1 / finalize2: unchanged.
// ---------------------------------------------------------------------------
__global__ __launch_bounds__(256) void finalize1_kernel(
    const float* __restrict__ partials, const float* __restrict__ en2G,
    const float* __restrict__ log_sigma, float* __restrict__ bsums) {
  __shared__ float buf[256];
  int idx = blockIdx.x * 256 + threadIdx.x;
  const float ls = log_sigma[0];
  const float sig = __expf(ls);
  const float ap = (-1.0f / (2.0f * sig * sig)) * 1.4426950408889634f;

  f32x4 p = *(const f32x4*)(partials + (size_t)idx * 4);
  float S = p[0] + p[1] + p[2] + p[3];
  float val = 0.69314718055994531f * (ap * en2G[idx] + log2f(S));

  buf[threadIdx.x] = val;
  __syncthreads();
  for (int s = 128; s; s >>= 1) {
    if (threadIdx.x < s) buf[threadIdx.x] += buf[threadIdx.x + s];
    __syncthreads();
  }
  if (threadIdx.x == 0) bsums[blockIdx.x] = buf[0];
}

__global__ __launch_bounds__(64) void finalize2_kernel(
    const float* __restrict__ bsums, const float* __restrict__ log_sigma,
    float* __restrict__ out_scalar) {
  float v = bsums[threadIdx.x];
  #pragma unroll
  for (int off = 32; off; off >>= 1) v += __shfl_down(v, off);
  if (threadIdx.x == 0) {
    float ls = log_sigma[0];
    float val = -v / (float)(L_L * N_B) + 0.5f * (float)D_D * (2.0f * ls - 1.0f)
              + logf((float)N_B);
    *out_scalar = val;
  }
}

extern "C" void kernel_launch(void* const* d_in, const int* in_sizes, int n_in,
                              void* d_out, int out_size, void* d_ws, size_t ws_size,
                              hipStream_t stream) {
  const float* z    = (const float*)d_in[0];
  const float* e    = (const float*)d_in[1];
  const float* encW = (const float*)d_in[2];
  const float* encb = (const float*)d_in[3];
  const float* decW = (const float*)d_in[4];
  const float* decb = (const float*)d_in[5];
  const float* lsg  = (const float*)d_in[6];

  float* out    = (float*)d_out;
  float* zdec   = out;                                // [2048*64]
  float* zmulti = out + N_B * D_D;                    // [8*2048*64]
  float* lse    = out + N_B * D_D + L_L * N_B * D_D;  // [1]

  float* partials = (float*)d_ws;                     // [8*2048*4]
  float* bsums    = partials + 65536;                 // [64]
  float* az       = bsums + 64;                       // [8*2048]
  float* en2      = az + 16384;                       // [8*2048]
  unsigned short* zh  = (unsigned short*)(en2 + 16384);  // [8*2048*64]
  unsigned short* zl  = zh + (1 << 20);
  unsigned short* dwh = zl + (1 << 20);               // [64*512]
  unsigned short* dwl = dwh + 32768;

  encode_kernel<<<256, 256, 0, stream>>>(z, encW, encb, decW, lsg,
                                         zmulti, zh, zl, az, dwh, dwl);
  lse_kernel<<<1024, 256, 0, stream>>>(zh, zl, e, az, lsg, partials, en2);
  zdec_kernel<<<128, 64, 0, stream>>>(zh, zl, dwh, dwl, decb, zdec);
  finalize1_kernel<<<64, 256, 0, stream>>>(partials, en2, lsg, bsums);
  finalize2_kernel<<<1, 64, 0, stream>>>(bsums, lsg, lse);
}

// Round 7
// 52.460 us; speedup vs baseline: 1.7537x; 1.1788x over previous
//
#include <hip/hip_runtime.h>
#include <math.h>

// Problem constants: N=2048, L=8, D=64, M=N=2048.
#define N_B 2048
#define L_L 8
#define D_D 64

typedef short bf16x8 __attribute__((ext_vector_type(8)));
typedef float f32x4 __attribute__((ext_vector_type(4)));
typedef unsigned short ushort8v __attribute__((ext_vector_type(8)));

// Split fp32 x into bf16 hi + bf16 lo (RTNE each), x ≈ hi+lo to ~2^-17 rel.
// Returns hi in high 16 bits, lo in low 16 bits.
__device__ __forceinline__ unsigned split_bf16_pack(float x) {
  unsigned u = __float_as_uint(x);
  unsigned rb = u + 0x7FFFu + ((u >> 16) & 1u);
  unsigned hbits = rb & 0xFFFF0000u;
  float res = x - __uint_as_float(hbits);
  unsigned u2 = __float_as_uint(res);
  unsigned rb2 = u2 + 0x7FFFu + ((u2 >> 16) & 1u);
  return hbits | (rb2 >> 16);
}

// Split 8 contiguous floats (optionally scaled) into hi/lo ushort8 vectors.
__device__ __forceinline__ void split8(const float* __restrict__ src,
                                       float scale, ushort8v& H, ushort8v& L,
                                       float* ssq) {
  float4 v0 = *(const float4*)(src);
  float4 v1 = *(const float4*)(src + 4);
  float vv[8] = {v0.x, v0.y, v0.z, v0.w, v1.x, v1.y, v1.z, v1.w};
  #pragma unroll
  for (int t = 0; t < 8; ++t) {
    if (ssq) *ssq += vv[t] * vv[t];
    unsigned p = split_bf16_pack(scale * vv[t]);
    H[t] = (unsigned short)(p >> 16);
    L[t] = (unsigned short)(p & 0xFFFF);
  }
}

// ---------------------------------------------------------------------------
// prep: one-time bf16 hi/lo split of all MFMA operands.
//  blocks [0,512):   e  (16384x64, scaled by se) -> esh/esl, en2 (raw ssq)
//  blocks [512,576): z  (2048x64)                -> zsh/zsl
//  blocks [576,592): encW (512x64)               -> ewh/ewl
//  blocks [592,608): decW (64x512)               -> dwh/dwl
// Each thread: 8 contiguous floats (fully coalesced).
// ---------------------------------------------------------------------------
__global__ __launch_bounds__(256) void prep_kernel(
    const float* __restrict__ z, const float* __restrict__ encW,
    const float* __restrict__ e, const float* __restrict__ decW,
    const float* __restrict__ log_sigma,
    unsigned short* __restrict__ zsh, unsigned short* __restrict__ zsl,
    unsigned short* __restrict__ ewh, unsigned short* __restrict__ ewl,
    unsigned short* __restrict__ esh, unsigned short* __restrict__ esl,
    float* __restrict__ en2G,
    unsigned short* __restrict__ dwh, unsigned short* __restrict__ dwl) {
  const int b = blockIdx.x;
  ushort8v H, L;
  if (b < 512) {
    const float ls = log_sigma[0];
    const float sig = __expf(ls);
    const float ap = (-1.0f / (2.0f * sig * sig)) * 1.4426950408889634f;
    const float se = -2.0f * ap;
    int t = b * 256 + threadIdx.x;          // 0..131071 (8 threads per e-row)
    size_t off = (size_t)t * 8;
    float ssq = 0.f;
    split8(e + off, se, H, L, &ssq);
    *(ushort8v*)(esh + off) = H;
    *(ushort8v*)(esl + off) = L;
    ssq += __shfl_xor(ssq, 1);
    ssq += __shfl_xor(ssq, 2);
    ssq += __shfl_xor(ssq, 4);
    if ((t & 7) == 0) en2G[t >> 3] = ssq;
  } else if (b < 576) {
    int t = (b - 512) * 256 + threadIdx.x;  // 0..16383
    size_t off = (size_t)t * 8;
    split8(z + off, 1.0f, H, L, nullptr);
    *(ushort8v*)(zsh + off) = H;
    *(ushort8v*)(zsl + off) = L;
  } else if (b < 592) {
    int t = (b - 576) * 256 + threadIdx.x;  // 0..4095
    size_t off = (size_t)t * 8;
    split8(encW + off, 1.0f, H, L, nullptr);
    *(ushort8v*)(ewh + off) = H;
    *(ushort8v*)(ewl + off) = L;
  } else {
    int t = (b - 592) * 256 + threadIdx.x;  // 0..4095
    size_t off = (size_t)t * 8;
    split8(decW + off, 1.0f, H, L, nullptr);
    *(ushort8v*)(dwh + off) = H;
    *(ushort8v*)(dwl + off) = L;
  }
}

// ---------------------------------------------------------------------------
// encode: h = z @ encW^T + encb as z_multi[l][n][d], all operands pre-split.
// grid 256 = nt(32) x l(8), block 256 = 4 waves x 16 n-rows.
// Emits zm (fp32 output), zh/zl (split of h), az (= ap*||h_row||^2).
// ---------------------------------------------------------------------------
__global__ __launch_bounds__(256) void encode_kernel(
    const unsigned short* __restrict__ zsh, const unsigned short* __restrict__ zsl,
    const unsigned short* __restrict__ ewh, const unsigned short* __restrict__ ewl,
    const float* __restrict__ encb, const float* __restrict__ log_sigma,
    float* __restrict__ zm,
    unsigned short* __restrict__ zhG, unsigned short* __restrict__ zlG,
    float* __restrict__ azG) {
  const int l = blockIdx.x & 7;
  const int nt = blockIdx.x >> 3;
  const int n0 = nt << 6;
  const int tid = threadIdx.x;
  const int lane = tid & 63;
  const int wave = tid >> 6;
  const int bm = lane & 15;
  const int kg = lane >> 4;
  const int k0 = kg << 3;

  const float ls = log_sigma[0];
  const float sig = __expf(ls);
  const float ap = (-1.0f / (2.0f * sig * sig)) * 1.4426950408889634f;

  // B fragments: encW rows i = l*64 + ms*16 + bm (pure loads)
  bf16x8 Bh0[4], Bh1[4], Bl0[4], Bl1[4];
  #pragma unroll
  for (int ms = 0; ms < 4; ++ms) {
    size_t base = ((size_t)(l * 64 + ms * 16 + bm)) * 64 + k0;
    Bh0[ms] = *(const bf16x8*)(ewh + base);
    Bh1[ms] = *(const bf16x8*)(ewh + base + 32);
    Bl0[ms] = *(const bf16x8*)(ewl + base);
    Bl1[ms] = *(const bf16x8*)(ewl + base + 32);
  }
  // A fragments: z rows n = n0 + wave*16 + bm
  bf16x8 ah0, ah1, al0, al1;
  {
    size_t base = ((size_t)(n0 + (wave << 4) + bm)) * 64 + k0;
    ah0 = *(const bf16x8*)(zsh + base);
    ah1 = *(const bf16x8*)(zsh + base + 32);
    al0 = *(const bf16x8*)(zsl + base);
    al1 = *(const bf16x8*)(zsl + base + 32);
  }

  float sq[4] = {0.f, 0.f, 0.f, 0.f};
  #pragma unroll
  for (int ms = 0; ms < 4; ++ms) {
    float bi = encb[l * 64 + ms * 16 + bm];
    f32x4 acc = {bi, bi, bi, bi};
    acc = __builtin_amdgcn_mfma_f32_16x16x32_bf16(ah0, Bh0[ms], acc, 0, 0, 0);
    acc = __builtin_amdgcn_mfma_f32_16x16x32_bf16(ah1, Bh1[ms], acc, 0, 0, 0);
    acc = __builtin_amdgcn_mfma_f32_16x16x32_bf16(al0, Bh0[ms], acc, 0, 0, 0);
    acc = __builtin_amdgcn_mfma_f32_16x16x32_bf16(al1, Bh1[ms], acc, 0, 0, 0);
    acc = __builtin_amdgcn_mfma_f32_16x16x32_bf16(ah0, Bl0[ms], acc, 0, 0, 0);
    acc = __builtin_amdgcn_mfma_f32_16x16x32_bf16(ah1, Bl1[ms], acc, 0, 0, 0);
    #pragma unroll
    for (int r = 0; r < 4; ++r) {
      float v = acc[r];
      int nr = n0 + (wave << 4) + (kg << 2) + r;
      size_t idx = ((size_t)(l * N_B + nr)) * 64 + (ms << 4) + bm;
      zm[idx] = v;
      unsigned p = split_bf16_pack(v);
      zhG[idx] = (unsigned short)(p >> 16);
      zlG[idx] = (unsigned short)(p & 0xFFFF);
      sq[r] += v * v;
    }
  }
  #pragma unroll
  for (int r = 0; r < 4; ++r) {
    float s = sq[r];
    s += __shfl_xor(s, 1);
    s += __shfl_xor(s, 2);
    s += __shfl_xor(s, 4);
    s += __shfl_xor(s, 8);
    if (bm == 0)
      azG[l * N_B + n0 + (wave << 4) + (kg << 2) + r] = ap * s;
  }
}

// ---------------------------------------------------------------------------
// lse: grid 1024 = l(8) x mt(32) x nb(4), XCD-swizzled (one l per XCD).
// All operands pre-split: prologue/main loop are pure loads + MFMA + exp2.
// partial[l][m][nb] = sum_n exp2( az_n + (-2ap) z_n.e_m )   [base-2 domain]
// ---------------------------------------------------------------------------
__global__ __launch_bounds__(256, 4) void lse_kernel(
    const unsigned short* __restrict__ zhG, const unsigned short* __restrict__ zlG,
    const unsigned short* __restrict__ esh, const unsigned short* __restrict__ esl,
    const float* __restrict__ azG, float* __restrict__ partials) {
  __shared__ float red[4][64];
  const int wgid = (blockIdx.x & 7) * 128 + (blockIdx.x >> 3);
  const int l = wgid >> 7;
  const int mt = (wgid >> 2) & 31;
  const int nb = wgid & 3;
  const int m0 = mt << 6;
  const int tid = threadIdx.x;
  const int lane = tid & 63;
  const int wave = tid >> 6;
  const int bm = lane & 15;
  const int kg = lane >> 4;
  const int k0 = kg << 3;

  // B fragments: pre-split scaled e rows (pure loads)
  bf16x8 Bh0[4], Bh1[4], Bl0[4], Bl1[4];
  #pragma unroll
  for (int ms = 0; ms < 4; ++ms) {
    size_t base = ((size_t)(l * N_B) + m0 + ms * 16 + bm) * 64 + k0;
    Bh0[ms] = *(const bf16x8*)(esh + base);
    Bh1[ms] = *(const bf16x8*)(esh + base + 32);
    Bl0[ms] = *(const bf16x8*)(esl + base);
    Bl1[ms] = *(const bf16x8*)(esl + base + 32);
  }

  float sums[4] = {0.f, 0.f, 0.f, 0.f};
  const unsigned short* zhL = zhG + (size_t)(l * N_B) * 64;
  const unsigned short* zlL = zlG + (size_t)(l * N_B) * 64;
  const float* azL = azG + l * N_B;

  #pragma unroll 2
  for (int c = 0; c < 8; ++c) {
    const int n0c = (nb << 9) + (((c << 2) + wave) << 4);
    const size_t abase = ((size_t)(n0c + bm)) * 64 + k0;
    bf16x8 ah0 = *(const bf16x8*)(zhL + abase);
    bf16x8 ah1 = *(const bf16x8*)(zhL + abase + 32);
    bf16x8 al0 = *(const bf16x8*)(zlL + abase);
    bf16x8 al1 = *(const bf16x8*)(zlL + abase + 32);
    f32x4 azv = *(const f32x4*)(azL + n0c + (kg << 2));
    #pragma unroll
    for (int ms = 0; ms < 4; ++ms) {
      f32x4 acc = {0.f, 0.f, 0.f, 0.f};
      acc = __builtin_amdgcn_mfma_f32_16x16x32_bf16(ah0, Bh0[ms], acc, 0, 0, 0);
      acc = __builtin_amdgcn_mfma_f32_16x16x32_bf16(ah1, Bh1[ms], acc, 0, 0, 0);
      acc = __builtin_amdgcn_mfma_f32_16x16x32_bf16(al0, Bh0[ms], acc, 0, 0, 0);
      acc = __builtin_amdgcn_mfma_f32_16x16x32_bf16(al1, Bh1[ms], acc, 0, 0, 0);
      acc = __builtin_amdgcn_mfma_f32_16x16x32_bf16(ah0, Bl0[ms], acc, 0, 0, 0);
      acc = __builtin_amdgcn_mfma_f32_16x16x32_bf16(ah1, Bl1[ms], acc, 0, 0, 0);
      sums[ms] += exp2f(acc[0] + azv[0]) + exp2f(acc[1] + azv[1]) +
                  exp2f(acc[2] + azv[2]) + exp2f(acc[3] + azv[3]);
    }
  }

  #pragma unroll
  for (int ms = 0; ms < 4; ++ms) {
    float s = sums[ms];
    s += __shfl_xor(s, 16);
    s += __shfl_xor(s, 32);
    if (lane < 16) red[wave][ms * 16 + lane] = s;
  }
  __syncthreads();
  if (tid < 64) {
    float S = red[0][tid] + red[1][tid] + red[2][tid] + red[3][tid];
    partials[(((size_t)(l * N_B)) + m0 + tid) * 4 + nb] = S;
  }
}

// ---------------------------------------------------------------------------
// zdec: z_dec = h @ decW^T + decb via split-bf16 MFMA over K=512.
// 128 blocks x 4 waves; each wave 4 of 16 K-groups; LDS cross-wave reduce.
// ---------------------------------------------------------------------------
__global__ __launch_bounds__(256) void zdec_kernel(
    const unsigned short* __restrict__ zhG, const unsigned short* __restrict__ zlG,
    const unsigned short* __restrict__ dwh, const unsigned short* __restrict__ dwl,
    const float* __restrict__ decb, float* __restrict__ zdec) {
  __shared__ f32x4 red[4][4][64];
  const int n0 = blockIdx.x << 4;
  const int tid = threadIdx.x;
  const int lane = tid & 63;
  const int wave = tid >> 6;
  const int bm = lane & 15;
  const int kg = lane >> 4;
  const int k0 = kg << 3;

  f32x4 acc[4] = {{0.f, 0.f, 0.f, 0.f}, {0.f, 0.f, 0.f, 0.f},
                  {0.f, 0.f, 0.f, 0.f}, {0.f, 0.f, 0.f, 0.f}};

  #pragma unroll
  for (int jj = 0; jj < 4; ++jj) {
    int j = (wave << 2) + jj;
    int l = j >> 1;
    int off = ((j & 1) << 5) + k0;
    size_t ab = ((size_t)(l * N_B + n0 + bm)) * 64 + off;
    bf16x8 ah = *(const bf16x8*)(zhG + ab);
    bf16x8 al = *(const bf16x8*)(zlG + ab);
    #pragma unroll
    for (int ms = 0; ms < 4; ++ms) {
      int d = (ms << 4) + bm;
      size_t bb = (size_t)d * 512 + (j << 5) + k0;
      bf16x8 bh = *(const bf16x8*)(dwh + bb);
      bf16x8 bl = *(const bf16x8*)(dwl + bb);
      acc[ms] = __builtin_amdgcn_mfma_f32_16x16x32_bf16(ah, bh, acc[ms], 0, 0, 0);
      acc[ms] = __builtin_amdgcn_mfma_f32_16x16x32_bf16(al, bh, acc[ms], 0, 0, 0);
      acc[ms] = __builtin_amdgcn_mfma_f32_16x16x32_bf16(ah, bl, acc[ms], 0, 0, 0);
    }
  }

  #pragma unroll
  for (int ms = 0; ms < 4; ++ms) red[wave][ms][lane] = acc[ms];
  __syncthreads();
  if (wave == 0) {
    #pragma unroll
    for (int ms = 0; ms < 4; ++ms) {
      f32x4 s = red[0][ms][lane];
      #pragma unroll
      for (int w = 1; w < 4; ++w) {
        f32x4 t = red[w][ms][lane];
        s[0] += t[0]; s[1] += t[1]; s[2] += t[2]; s[3] += t[3];
      }
      float bd = decb[(ms << 4) + bm];
      #pragma unroll
      for (int r = 0; r < 4; ++r)
        zdec[(size_t)(n0 + (kg << 2) + r) * 64 + (ms << 4) + bm] = s[r] + bd;
    }
  }
}

// ---------------------------------------------------------------------------
// finalize1: per (l,m): S = sum of 4 nb-partials; val = ln2*(ap*en2+log2 S);
// block-sum -> bsums[64].
// ---------------------------------------------------------------------------
__global__ __launch_bounds__(256) void finalize1_kernel(
    const float* __restrict__ partials, const float* __restrict__ en2G,
    const float* __restrict__ log_sigma, float* __restrict__ bsums) {
  __shared__ float buf[256];
  int idx = blockIdx.x * 256 + threadIdx.x;
  const float ls = log_sigma[0];
  const float sig = __expf(ls);
  const float ap = (-1.0f / (2.0f * sig * sig)) * 1.4426950408889634f;

  f32x4 p = *(const f32x4*)(partials + (size_t)idx * 4);
  float S = p[0] + p[1] + p[2] + p[3];
  float val = 0.69314718055994531f * (ap * en2G[idx] + log2f(S));

  buf[threadIdx.x] = val;
  __syncthreads();
  for (int s = 128; s; s >>= 1) {
    if (threadIdx.x < s) buf[threadIdx.x] += buf[threadIdx.x + s];
    __syncthreads();
  }
  if (threadIdx.x == 0) bsums[blockIdx.x] = buf[0];
}

__global__ __launch_bounds__(64) void finalize2_kernel(
    const float* __restrict__ bsums, const float* __restrict__ log_sigma,
    float* __restrict__ out_scalar) {
  float v = bsums[threadIdx.x];
  #pragma unroll
  for (int off = 32; off; off >>= 1) v += __shfl_down(v, off);
  if (threadIdx.x == 0) {
    float ls = log_sigma[0];
    float val = -v / (float)(L_L * N_B) + 0.5f * (float)D_D * (2.0f * ls - 1.0f)
              + logf((float)N_B);
    *out_scalar = val;
  }
}

extern "C" void kernel_launch(void* const* d_in, const int* in_sizes, int n_in,
                              void* d_out, int out_size, void* d_ws, size_t ws_size,
                              hipStream_t stream) {
  const float* z    = (const float*)d_in[0];
  const float* e    = (const float*)d_in[1];
  const float* encW = (const float*)d_in[2];
  const float* encb = (const float*)d_in[3];
  const float* decW = (const float*)d_in[4];
  const float* decb = (const float*)d_in[5];
  const float* lsg  = (const float*)d_in[6];

  float* out    = (float*)d_out;
  float* zdec   = out;                                // [2048*64]
  float* zmulti = out + N_B * D_D;                    // [8*2048*64]
  float* lse    = out + N_B * D_D + L_L * N_B * D_D;  // [1]

  float* partials = (float*)d_ws;                     // [65536]
  float* bsums    = partials + 65536;                 // [64] (pad to 128)
  float* az       = partials + 65664;                 // [16384]
  float* en2      = az + 16384;                       // [16384]
  unsigned short* us = (unsigned short*)(en2 + 16384);
  unsigned short* zsh = us;                 // [131072]
  unsigned short* zsl = zsh + 131072;
  unsigned short* ewh = zsl + 131072;       // [32768]
  unsigned short* ewl = ewh + 32768;
  unsigned short* esh = ewl + 32768;        // [1048576]
  unsigned short* esl = esh + 1048576;
  unsigned short* dwh = esl + 1048576;      // [32768]
  unsigned short* dwl = dwh + 32768;
  unsigned short* zh  = dwl + 32768;        // [1048576]
  unsigned short* zl  = zh + 1048576;

  prep_kernel<<<608, 256, 0, stream>>>(z, encW, e, decW, lsg,
                                       zsh, zsl, ewh, ewl, esh, esl, en2,
                                       dwh, dwl);
  encode_kernel<<<256, 256, 0, stream>>>(zsh, zsl, ewh, ewl, encb, lsg,
                                         zmulti, zh, zl, az);
  lse_kernel<<<1024, 256, 0, stream>>>(zh, zl, esh, esl, az, partials);
  zdec_kernel<<<128, 256, 0, stream>>>(zh, zl, dwh, dwl, decb, zdec);
  finalize1_kernel<<<64, 256, 0, stream>>>(partials, en2, lsg, bsums);
  finalize2_kernel<<<1, 64, 0, stream>>>(bsums, lsg, lse);
}